// Round 1
// baseline (113219.446 us; speedup 1.0000x reference)
//
#include <hip/hip_runtime.h>
#include <hip/hip_cooperative_groups.h>

namespace cg = cooperative_groups;

#define Bx 128
#define Sx 512
#define Fx 64
#define Hx 512
#define Xx 128   // 2F

// ---- workspace float offsets ----
#define MF_OFF   0ull
#define H_OFF    4194304ull                    // mf is [B][S][F] = 4,194,304 floats
#define XH_OFF   (H_OFF + 2ull*2*Bx*Hx)        // h[2 dir][2 ping][B][H]
#define FLAG_OFF (XH_OFF + 2ull*Bx*Fx)         // xhat_buf[2][B][F]

// ---- LDS word offsets ----
// whh slice: [3 gates][16 units][8 chunks][68 words] (64 data + 4 pad; quad=jq balanced)
#define LDSW_WHH   0
#define LDSW_XIN   26112                       // 3*16*8*68
#define LDSW_WRO   (LDSW_XIN + 32*160)         // xin: [32 b][8 chunks][20 words]
#define LDSW_WOUT  (LDSW_WRO + 2*544)          // wro: [2 f][8 chunks][68]
#define LDSW_TOTAL (LDSW_WOUT + 2*544)         // = 33408 floats = 133,632 B

struct BParams {
  const float* x;
  const float* Wih_f; const float* Whh_f; const float* bih_f; const float* bhh_f;
  const float* Wro_f; const float* bro_f;
  const float* Wih_b; const float* Whh_b; const float* bih_b; const float* bhh_b;
  const float* Wro_b; const float* bro_b;
  const float* Wout; const float* bout;
  float* out; float* ws;
};

__global__ void detect_kernel(const unsigned int* mask, int* flag) {
  if (threadIdx.x == 0) *flag = 0;
  __syncthreads();
  unsigned int v = 0;
  for (int i = threadIdx.x; i < 4096; i += blockDim.x) v |= mask[i] & 0xFFFFFF00u;
  if (v) atomicOr(flag, 1);
}

__global__ void mf_kernel(const unsigned char* m8, const int* m32, const int* flag,
                          float* mf, int n) {
  const int u8 = *flag;
  int i = blockIdx.x * blockDim.x + threadIdx.x;
  const int stride = gridDim.x * blockDim.x;
  for (; i < n; i += stride) mf[i] = u8 ? (float)m8[i] : (float)m32[i];
}

__device__ inline void fma4(float& a, float4 w, float4 h) {
  a = fmaf(w.x, h.x, a); a = fmaf(w.y, h.y, a);
  a = fmaf(w.z, h.z, a); a = fmaf(w.w, h.w, a);
}

__device__ inline float sel8(const float* a, int idx) {
  float v = a[0];
#pragma unroll
  for (int i = 1; i < 8; ++i) v = (idx == i) ? a[i] : v;
  return v;
}

__global__ void __launch_bounds__(512, 2)
birnn_main(BParams p) {
  extern __shared__ float lds[];
  cg::grid_group grid = cg::this_grid();

  const int w   = blockIdx.x;
  const int dir = w & 1;
  const int gg  = w >> 1;        // 0..127
  const int bg  = gg & 3;        // batch group (32 batches)
  const int hs  = gg >> 2;       // hidden slice (16 units), also f-slice (2 outs)
  const int b0  = bg * 32;
  const int u0  = hs * 16;
  const int f0  = hs * 2;
  const int tid = threadIdx.x;

  const float* Wih = dir ? p.Wih_b : p.Wih_f;
  const float* Whh = dir ? p.Whh_b : p.Whh_f;
  const float* bih = dir ? p.bih_b : p.bih_f;
  const float* bhh = dir ? p.bhh_b : p.bhh_f;
  const float* Wro = dir ? p.Wro_b : p.Wro_f;
  const float* bro = dir ? p.bro_b : p.bro_f;

  float* hbuf = p.ws + H_OFF;
  float* xhb  = p.ws + XH_OFF;
  const float* mf = p.ws + MF_OFF;
  float* out_xhat = p.out;
  float* out_xh   = p.out + (size_t)(1 + dir) * Bx * Sx * Fx;

  // ---- preload LDS-resident weight slices ----
  for (int idx = tid; idx < 3 * 16 * 512; idx += 512) {
    int g3 = idx >> 13; int rem = idx & 8191;
    int u = rem >> 9;   int j = rem & 511;
    lds[LDSW_WHH + ((g3 * 16 + u) * 8 + (j >> 6)) * 68 + (j & 63)] =
        Whh[(size_t)(g3 * 512 + u0 + u) * Hx + j];
  }
  for (int idx = tid; idx < 2 * 512; idx += 512) {
    int f = idx >> 9, j = idx & 511;
    lds[LDSW_WRO  + f * 544 + (j >> 6) * 68 + (j & 63)] = Wro[(size_t)(f0 + f) * Hx + j];
    lds[LDSW_WOUT + f * 544 + (j >> 6) * 68 + (j & 63)] =
        p.Wout[(size_t)(f0 + f) * (2 * Hx) + dir * Hx + j];
  }

  // ---- init: h(buf0)=0, xhat=bro, outputs at the boundary time index ----
  if (hs == 0) {
    for (int idx = tid; idx < 32 * 512; idx += 512) {
      int b = b0 + (idx >> 9), j = idx & 511;
      hbuf[((size_t)(dir * 2 + 0) * Bx + b) * Hx + j] = 0.f;
    }
  }
  if (tid < 64) {
    int b = b0 + (tid >> 1), f = f0 + (tid & 1);
    float br = bro[f];
    xhb[((size_t)dir * Bx + b) * Fx + f] = br;
    int T0 = dir ? (Sx - 1) : 0;
    out_xh  [((size_t)b * Sx + T0) * Fx + f] = br;
    out_xhat[((size_t)b * Sx + T0) * Fx + f] = p.bout[f];   // h=0 contribution
  }
  __threadfence();
  grid.sync();

  // phase-A thread map: lane = jq(3b) x ulo(3b); wave = bsub(2b) x uhi(1b)
  const int jq   = tid & 7;
  const int ulo  = (tid >> 3) & 7;
  const int wv   = tid >> 6;
  const int bsub = wv & 3;
  const int uhi  = wv >> 2;
  const int u    = uhi * 8 + ulo;
  const int bA   = b0 + bsub * 8;
  // phase-B thread map: lane = jq(3b) x blo(3b); wave = bhi(2b) x fB(1b)
  const int blo  = (tid >> 3) & 7;
  const int bB   = b0 + (wv & 3) * 8 + blo;
  const int fB   = wv >> 2;

  for (int k = 1; k < Sx; ++k) {
    const int pp = k & 1, pr = pp ^ 1;
    const int t_in = dir ? (Sx - k) : (k - 1);

    // ---- stage x_in = [x_p, m] into LDS ----
    {
      int bl = tid >> 4, sub = tid & 15;
      int b = b0 + bl;
      size_t base = ((size_t)b * Sx + t_in) * Fx;
      float* xr = lds + LDSW_XIN + bl * 160;
#pragma unroll
      for (int cc = 0; cc < 8; ++cc) {
        int c = sub * 8 + cc;
        float v;
        if (c < Fx) {
          float mv = mf[base + c];
          v = mv * p.x[base + c] +
              (1.f - mv) * xhb[((size_t)dir * Bx + b) * Fx + c];
        } else {
          v = mf[base + (c - Fx)];
        }
        xr[(c >> 4) * 20 + (c & 15)] = v;
      }
    }
    __syncthreads();

    float acc0[8], acc1[8], acc2[8], acc3[8];
#pragma unroll
    for (int i = 0; i < 8; ++i) { acc0[i] = 0.f; acc1[i] = 0.f; acc2[i] = 0.f; acc3[i] = 0.f; }

    // ---- gh: Whh slice (LDS) x h_prev (global) ----
    {
      const float* hrd = hbuf + (size_t)(dir * 2 + pr) * Bx * Hx;
      const float* w0p = lds + LDSW_WHH + ((0 * 16 + u) * 8 + jq) * 68;
      const float* w1p = lds + LDSW_WHH + ((1 * 16 + u) * 8 + jq) * 68;
      const float* w2p = lds + LDSW_WHH + ((2 * 16 + u) * 8 + jq) * 68;
      const int j0 = jq * 64;
#pragma unroll 2
      for (int jj = 0; jj < 64; jj += 4) {
        float4 w0 = *(const float4*)(w0p + jj);
        float4 w1 = *(const float4*)(w1p + jj);
        float4 w2 = *(const float4*)(w2p + jj);
#pragma unroll
        for (int bb = 0; bb < 8; ++bb) {
          float4 h4 = *(const float4*)(hrd + (size_t)(bA + bb) * Hx + j0 + jj);
          fma4(acc0[bb], w0, h4);
          fma4(acc1[bb], w1, h4);
          fma4(acc3[bb], w2, h4);
        }
      }
    }
    // ---- gi: Wih rows (global/L2) x x_in (LDS) ----
    {
      const float* xinb = lds + LDSW_XIN;
      const float* wr0 = Wih + (size_t)(0 * 512 + u0 + u) * Xx + jq * 16;
      const float* wr1 = Wih + (size_t)(1 * 512 + u0 + u) * Xx + jq * 16;
      const float* wr2 = Wih + (size_t)(2 * 512 + u0 + u) * Xx + jq * 16;
#pragma unroll 2
      for (int cc = 0; cc < 16; cc += 4) {
        float4 w0 = *(const float4*)(wr0 + cc);
        float4 w1 = *(const float4*)(wr1 + cc);
        float4 w2 = *(const float4*)(wr2 + cc);
        int off = jq * 20 + cc;
#pragma unroll
        for (int bb = 0; bb < 8; ++bb) {
          float4 xv = *(const float4*)(xinb + (bsub * 8 + bb) * 160 + off);
          fma4(acc0[bb], w0, xv);
          fma4(acc1[bb], w1, xv);
          fma4(acc2[bb], w2, xv);
        }
      }
    }
    // ---- reduce partial sums across jq (lane bits 0..2) ----
#pragma unroll
    for (int m = 1; m <= 4; m <<= 1) {
#pragma unroll
      for (int bb = 0; bb < 8; ++bb) {
        acc0[bb] += __shfl_xor(acc0[bb], m);
        acc1[bb] += __shfl_xor(acc1[bb], m);
        acc2[bb] += __shfl_xor(acc2[bb], m);
        acc3[bb] += __shfl_xor(acc3[bb], m);
      }
    }
    // ---- gates: lane jq handles batch bA+jq ----
    {
      const float* hrd = hbuf + (size_t)(dir * 2 + pr) * Bx * Hx;
      int b = bA + jq;
      float sr  = sel8(acc0, jq);
      float sz  = sel8(acc1, jq);
      float sgi = sel8(acc2, jq);
      float sgh = sel8(acc3, jq);
      int ru = u0 + u;
      float r = 1.f / (1.f + __expf(-(sr + bih[ru] + bhh[ru])));
      float z = 1.f / (1.f + __expf(-(sz + bih[512 + ru] + bhh[512 + ru])));
      float n = tanhf(sgi + bih[1024 + ru] + r * (sgh + bhh[1024 + ru]));
      float ho = hrd[(size_t)b * Hx + ru];
      hbuf[(size_t)(dir * 2 + pp) * Bx * Hx + (size_t)b * Hx + ru] =
          (1.f - z) * n + z * ho;
    }
    __threadfence();
    grid.sync();

    // ---- phase B: xhat = Wro@h + bro ; x_hat partial = Wout_half@h ----
    {
      const float* hnw  = hbuf + (size_t)(dir * 2 + pp) * Bx * Hx;
      const float* wroL = lds + LDSW_WRO  + fB * 544 + jq * 68;
      const float* wouL = lds + LDSW_WOUT + fB * 544 + jq * 68;
      const float* hb   = hnw + (size_t)bB * Hx + jq * 64;
      float ax = 0.f, ap = 0.f;
#pragma unroll 2
      for (int jj = 0; jj < 64; jj += 4) {
        float4 h4 = *(const float4*)(hb + jj);
        float4 wx = *(const float4*)(wroL + jj);
        float4 wp = *(const float4*)(wouL + jj);
        fma4(ax, wx, h4);
        fma4(ap, wp, h4);
      }
#pragma unroll
      for (int m = 1; m <= 4; m <<= 1) {
        ax += __shfl_xor(ax, m);
        ap += __shfl_xor(ap, m);
      }
      const int T = dir ? (Sx - 1 - k) : k;
      const int f = f0 + fB;
      if (jq == 0) {
        float v = ax + bro[f];
        xhb[((size_t)dir * Bx + bB) * Fx + f] = v;
        out_xh[((size_t)bB * Sx + T) * Fx + f] = v;
      } else if (jq == 1) {
        size_t o = ((size_t)bB * Sx + T) * Fx + f;
        if (k <= 255) out_xhat[o] = ap + p.bout[f];   // first writer for this T
        else          out_xhat[o] = out_xhat[o] + ap; // second contributor adds
      }
    }
    __threadfence();
    grid.sync();
  }
}

extern "C" void kernel_launch(void* const* d_in, const int* in_sizes, int n_in,
                              void* d_out, int out_size, void* d_ws, size_t ws_size,
                              hipStream_t stream) {
  (void)in_sizes; (void)n_in; (void)out_size; (void)ws_size;
  float* ws = (float*)d_ws;
  int* flag = (int*)(ws + FLAG_OFF);

  detect_kernel<<<1, 256, 0, stream>>>((const unsigned int*)d_in[1], flag);
  mf_kernel<<<1024, 256, 0, stream>>>((const unsigned char*)d_in[1],
                                      (const int*)d_in[1], flag,
                                      ws + MF_OFF, Bx * Sx * Fx);

  BParams p;
  p.x     = (const float*)d_in[0];
  p.Wih_f = (const float*)d_in[2];  p.Whh_f = (const float*)d_in[3];
  p.bih_f = (const float*)d_in[4];  p.bhh_f = (const float*)d_in[5];
  p.Wro_f = (const float*)d_in[6];  p.bro_f = (const float*)d_in[7];
  p.Wih_b = (const float*)d_in[8];  p.Whh_b = (const float*)d_in[9];
  p.bih_b = (const float*)d_in[10]; p.bhh_b = (const float*)d_in[11];
  p.Wro_b = (const float*)d_in[12]; p.bro_b = (const float*)d_in[13];
  p.Wout  = (const float*)d_in[14]; p.bout  = (const float*)d_in[15];
  p.out   = (float*)d_out;
  p.ws    = ws;

  hipFuncSetAttribute(reinterpret_cast<const void*>(birnn_main),
                      hipFuncAttributeMaxDynamicSharedMemorySize,
                      (int)(LDSW_TOTAL * sizeof(float)));
  void* args[] = { (void*)&p };
  hipLaunchCooperativeKernel(reinterpret_cast<void*>(birnn_main),
                             dim3(256), dim3(512), args,
                             (unsigned)(LDSW_TOTAL * sizeof(float)), stream);
}

// Round 2
// 32321.024 us; speedup vs baseline: 3.5030x; 3.5030x over previous
//
#include <hip/hip_runtime.h>

#define Bx 128
#define Sx 512
#define Fx 64
#define Hx 512
#define Xx 128   // 2F

// ---- workspace float offsets ----
#define PARTB_OFF 0ull                             // bwd Wout-partial [B][S][F]
#define H_OFF     ((size_t)Bx * Sx * Fx)           // 4,194,304
#define XH_OFF    (H_OFF + (size_t)2 * 2 * Bx * Hx)
#define BAR_OFF   (XH_OFF + (size_t)2 * Bx * Fx)   // 8 groups x 16 ints
#define FLAG_OFF  (BAR_OFF + 128)

// ---- LDS word offsets ----
#define LDSW_WHH   0
#define LDSW_XIN   26112                       // 3*16*8*68
#define LDSW_WRO   (LDSW_XIN + 32 * 160)
#define LDSW_WOUT  (LDSW_WRO + 2 * 544)
#define LDSW_TOTAL (LDSW_WOUT + 2 * 544)       // 33408 floats = 133,632 B

struct BParams {
  const float* x; const void* mask;
  const float* Wih_f; const float* Whh_f; const float* bih_f; const float* bhh_f;
  const float* Wro_f; const float* bro_f;
  const float* Wih_b; const float* Whh_b; const float* bih_b; const float* bhh_b;
  const float* Wro_b; const float* bro_b;
  const float* Wout; const float* bout;
  float* out; float* ws;
};

__global__ void detect_kernel(const unsigned int* mask, float* ws) {
  int* bars = (int*)(ws + BAR_OFF);
  int* flag = (int*)(ws + FLAG_OFF);
  int t = threadIdx.x;
  if (t < 128) bars[t] = 0;
  if (t == 128) *flag = 0;
  __syncthreads();
  unsigned int v = 0;
  for (int i = t; i < 4096; i += blockDim.x) v |= mask[i] & 0xFFFFFF00u;
  if (v) atomicOr(flag, 1);
}

__global__ void combine_kernel(float* out, const float* partb, const float* bout) {
  int i = blockIdx.x * blockDim.x + threadIdx.x;
  out[i] = out[i] + partb[i] + bout[i & 63];
}

__device__ __forceinline__ void fma4(float& a, float4 w, float4 h) {
  a = fmaf(w.x, h.x, a); a = fmaf(w.y, h.y, a);
  a = fmaf(w.z, h.z, a); a = fmaf(w.w, h.w, a);
}

__device__ __forceinline__ float sel8(const float* a, int idx) {
  float v = a[0];
#pragma unroll
  for (int i = 1; i < 8; ++i) v = (idx == i) ? a[i] : v;
  return v;
}

// 32-member group barrier. Monotonic counter; only thread 0 touches device
// scope. Entry __syncthreads drains every wave's stores to L2 (compiler emits
// vmcnt(0) before s_barrier); the RELEASE fetch_add emits the L2 writeback, so
// all h/xhb stores are at coherence point before arrival. Works for ANY
// wg->XCD placement.
__device__ __forceinline__ void group_barrier(int* bar, int target) {
  __syncthreads();
  if (threadIdx.x == 0) {
    __hip_atomic_fetch_add(bar, 1, __ATOMIC_RELEASE, __HIP_MEMORY_SCOPE_AGENT);
    while (__hip_atomic_load(bar, __ATOMIC_RELAXED, __HIP_MEMORY_SCOPE_AGENT) < target)
      __builtin_amdgcn_s_sleep(2);
    __threadfence();   // acquire: invalidate stale L1/L2 before readers proceed
  }
  __syncthreads();
}

__global__ void __launch_bounds__(512, 2)
birnn_main(BParams p) {
  extern __shared__ float lds[];

  const int w   = blockIdx.x;
  const int g   = w & 7;         // group = (dir, batch-group); likely one XCD
  const int dir = g >> 2;
  const int bg  = g & 3;
  const int hs  = w >> 3;        // hidden slice 0..31
  const int b0  = bg * 32;
  const int u0  = hs * 16;
  const int f0  = hs * 2;
  const int tid = threadIdx.x;

  const float* Wih = dir ? p.Wih_b : p.Wih_f;
  const float* Whh = dir ? p.Whh_b : p.Whh_f;
  const float* bih = dir ? p.bih_b : p.bih_f;
  const float* bhh = dir ? p.bhh_b : p.bhh_f;
  const float* Wro = dir ? p.Wro_b : p.Wro_f;
  const float* bro = dir ? p.bro_b : p.bro_f;

  float* hbuf = p.ws + H_OFF;
  float* xhb  = p.ws + XH_OFF;
  int*   bar  = (int*)(p.ws + BAR_OFF) + g * 16;
  const int u8f = *(const int*)(p.ws + FLAG_OFF);
  const unsigned char* m8  = (const unsigned char*)p.mask;
  const int*           m32 = (const int*)p.mask;

  float* pout   = dir ? (p.ws + PARTB_OFF) : p.out;  // Wout half-partials
  float* out_xh = p.out + (size_t)(1 + dir) * Bx * Sx * Fx;

  // ---- preload LDS-resident weight slices ----
  for (int idx = tid; idx < 3 * 16 * 512; idx += 512) {
    int g3 = idx >> 13; int rem = idx & 8191;
    int u = rem >> 9;   int j = rem & 511;
    lds[LDSW_WHH + ((g3 * 16 + u) * 8 + (j >> 6)) * 68 + (j & 63)] =
        Whh[(size_t)(g3 * 512 + u0 + u) * Hx + j];
  }
  for (int idx = tid; idx < 2 * 512; idx += 512) {
    int f = idx >> 9, j = idx & 511;
    lds[LDSW_WRO  + f * 544 + (j >> 6) * 68 + (j & 63)] = Wro[(size_t)(f0 + f) * Hx + j];
    lds[LDSW_WOUT + f * 544 + (j >> 6) * 68 + (j & 63)] =
        p.Wout[(size_t)(f0 + f) * (2 * Hx) + dir * Hx + j];
  }

  // ---- init: h=0, xhat=bro, boundary outputs ----
  if (hs == 0) {
    for (int idx = tid; idx < 32 * 512; idx += 512) {
      int b = b0 + (idx >> 9), j = idx & 511;
      hbuf[((size_t)(dir * 2 + 0) * Bx + b) * Hx + j] = 0.f;
    }
  }
  if (tid < 64) {
    int b = b0 + (tid >> 1), f = f0 + (tid & 1);
    float br = bro[f];
    xhb[((size_t)dir * Bx + b) * Fx + f] = br;
    int T0 = dir ? (Sx - 1) : 0;
    out_xh[((size_t)b * Sx + T0) * Fx + f] = br;
    pout  [((size_t)b * Sx + T0) * Fx + f] = 0.f;   // h=0 -> zero partial
  }

  // phase-A map: lane = jq(3b) x ulo(3b); wave = bsub(2b) x uhi(1b)
  const int jq   = tid & 7;
  const int ulo  = (tid >> 3) & 7;
  const int wv   = tid >> 6;
  const int bsub = wv & 3;
  const int uhi  = wv >> 2;
  const int u    = uhi * 8 + ulo;
  const int bA   = b0 + bsub * 8;
  const int ru   = u0 + u;
  // phase-B map: lane = jq(3b) x blo(3b); wave = bhi(2b) x fB(1b)
  const int blo  = (tid >> 3) & 7;
  const int bB   = b0 + (wv & 3) * 8 + blo;
  const int fB   = wv >> 2;

  // per-thread-invariant Wih rows + gate biases -> registers (survive L2 inv)
  float4 wih0[4], wih1[4], wih2[4];
#pragma unroll
  for (int q = 0; q < 4; ++q) {
    wih0[q] = *(const float4*)(Wih + (size_t)(0 * 512 + ru) * Xx + jq * 16 + q * 4);
    wih1[q] = *(const float4*)(Wih + (size_t)(1 * 512 + ru) * Xx + jq * 16 + q * 4);
    wih2[q] = *(const float4*)(Wih + (size_t)(2 * 512 + ru) * Xx + jq * 16 + q * 4);
  }
  const float bs_r = bih[ru] + bhh[ru];
  const float bs_z = bih[512 + ru] + bhh[512 + ru];
  const float bs_i = bih[1024 + ru];
  const float bs_h = bhh[1024 + ru];

  const float* w0p = lds + LDSW_WHH + ((0 * 16 + u) * 8 + jq) * 68;
  const float* w1p = lds + LDSW_WHH + ((1 * 16 + u) * 8 + jq) * 68;
  const float* w2p = lds + LDSW_WHH + ((2 * 16 + u) * 8 + jq) * 68;

  int bt = 32;
  group_barrier(bar, bt);   // publish init

  for (int k = 1; k < Sx; ++k) {
    const int pp = k & 1, pr = pp ^ 1;
    const int t_in = dir ? (Sx - k) : (k - 1);

    // ---- stage x_in = [x_p, m] into LDS ----
    {
      int bl = tid >> 4, sub = tid & 15;
      int b = b0 + bl;
      size_t base = ((size_t)b * Sx + t_in) * Fx;
      float* xr = lds + LDSW_XIN + bl * 160;
#pragma unroll
      for (int cc = 0; cc < 8; ++cc) {
        int c = sub * 8 + cc;
        float v;
        if (c < Fx) {
          float mv = u8f ? (float)m8[base + c] : (float)m32[base + c];
          v = mv * p.x[base + c] +
              (1.f - mv) * xhb[((size_t)dir * Bx + b) * Fx + c];
        } else {
          v = u8f ? (float)m8[base + c - Fx] : (float)m32[base + c - Fx];
        }
        xr[(c >> 4) * 20 + (c & 15)] = v;
      }
    }
    __syncthreads();

    float acc0[8], acc1[8], acc2[8], acc3[8];
#pragma unroll
    for (int i = 0; i < 8; ++i) { acc0[i] = 0.f; acc1[i] = 0.f; acc2[i] = 0.f; acc3[i] = 0.f; }

    // ---- gh: Whh slice (LDS) x h_prev (global) ----
    {
      const float* hrd = hbuf + (size_t)(dir * 2 + pr) * Bx * Hx;
      const int j0 = jq * 64;
#pragma unroll 2
      for (int jj = 0; jj < 64; jj += 4) {
        float4 w0 = *(const float4*)(w0p + jj);
        float4 w1 = *(const float4*)(w1p + jj);
        float4 w2 = *(const float4*)(w2p + jj);
#pragma unroll
        for (int bb = 0; bb < 8; ++bb) {
          float4 h4 = *(const float4*)(hrd + (size_t)(bA + bb) * Hx + j0 + jj);
          fma4(acc0[bb], w0, h4);
          fma4(acc1[bb], w1, h4);
          fma4(acc3[bb], w2, h4);
        }
      }
    }
    // ---- gi: Wih rows (registers) x x_in (LDS) ----
    {
      const float* xinb = lds + LDSW_XIN;
#pragma unroll
      for (int q = 0; q < 4; ++q) {
        float4 w0 = wih0[q], w1 = wih1[q], w2 = wih2[q];
        int off = jq * 20 + q * 4;
#pragma unroll
        for (int bb = 0; bb < 8; ++bb) {
          float4 xv = *(const float4*)(xinb + (bsub * 8 + bb) * 160 + off);
          fma4(acc0[bb], w0, xv);
          fma4(acc1[bb], w1, xv);
          fma4(acc2[bb], w2, xv);
        }
      }
    }
    // ---- reduce across jq ----
#pragma unroll
    for (int m = 1; m <= 4; m <<= 1) {
#pragma unroll
      for (int bb = 0; bb < 8; ++bb) {
        acc0[bb] += __shfl_xor(acc0[bb], m);
        acc1[bb] += __shfl_xor(acc1[bb], m);
        acc2[bb] += __shfl_xor(acc2[bb], m);
        acc3[bb] += __shfl_xor(acc3[bb], m);
      }
    }
    // ---- gates ----
    {
      const float* hrd = hbuf + (size_t)(dir * 2 + pr) * Bx * Hx;
      int b = bA + jq;
      float sr  = sel8(acc0, jq);
      float sz  = sel8(acc1, jq);
      float sgi = sel8(acc2, jq);
      float sgh = sel8(acc3, jq);
      float r = 1.f / (1.f + __expf(-(sr + bs_r)));
      float z = 1.f / (1.f + __expf(-(sz + bs_z)));
      float n = tanhf(sgi + bs_i + r * (sgh + bs_h));
      float ho = hrd[(size_t)b * Hx + ru];
      hbuf[(size_t)(dir * 2 + pp) * Bx * Hx + (size_t)b * Hx + ru] =
          (1.f - z) * n + z * ho;
    }
    bt += 32;
    group_barrier(bar, bt);   // h_new visible to group

    // ---- phase B: xhat = Wro@h + bro ; Wout-half partial ----
    {
      const float* hnw  = hbuf + (size_t)(dir * 2 + pp) * Bx * Hx;
      const float* wroL = lds + LDSW_WRO  + fB * 544 + jq * 68;
      const float* wouL = lds + LDSW_WOUT + fB * 544 + jq * 68;
      const float* hb   = hnw + (size_t)bB * Hx + jq * 64;
      float ax = 0.f, ap = 0.f;
#pragma unroll 2
      for (int jj = 0; jj < 64; jj += 4) {
        float4 h4 = *(const float4*)(hb + jj);
        float4 wx = *(const float4*)(wroL + jj);
        float4 wp = *(const float4*)(wouL + jj);
        fma4(ax, wx, h4);
        fma4(ap, wp, h4);
      }
#pragma unroll
      for (int m = 1; m <= 4; m <<= 1) {
        ax += __shfl_xor(ax, m);
        ap += __shfl_xor(ap, m);
      }
      const int T = dir ? (Sx - 1 - k) : k;
      const int f = f0 + fB;
      if (jq == 0) {
        float v = ax + bro[f];
        xhb[((size_t)dir * Bx + bB) * Fx + f] = v;
        out_xh[((size_t)bB * Sx + T) * Fx + f] = v;
      } else if (jq == 1) {
        pout[((size_t)bB * Sx + T) * Fx + f] = ap;   // pure write, no RMW
      }
    }
    bt += 32;
    group_barrier(bar, bt);   // xhb visible for next stage
  }
}

extern "C" void kernel_launch(void* const* d_in, const int* in_sizes, int n_in,
                              void* d_out, int out_size, void* d_ws, size_t ws_size,
                              hipStream_t stream) {
  (void)in_sizes; (void)n_in; (void)out_size; (void)ws_size;
  float* ws = (float*)d_ws;

  detect_kernel<<<1, 256, 0, stream>>>((const unsigned int*)d_in[1], ws);

  BParams p;
  p.x     = (const float*)d_in[0];  p.mask = d_in[1];
  p.Wih_f = (const float*)d_in[2];  p.Whh_f = (const float*)d_in[3];
  p.bih_f = (const float*)d_in[4];  p.bhh_f = (const float*)d_in[5];
  p.Wro_f = (const float*)d_in[6];  p.bro_f = (const float*)d_in[7];
  p.Wih_b = (const float*)d_in[8];  p.Whh_b = (const float*)d_in[9];
  p.bih_b = (const float*)d_in[10]; p.bhh_b = (const float*)d_in[11];
  p.Wro_b = (const float*)d_in[12]; p.bro_b = (const float*)d_in[13];
  p.Wout  = (const float*)d_in[14]; p.bout  = (const float*)d_in[15];
  p.out   = (float*)d_out;
  p.ws    = ws;

  hipFuncSetAttribute(reinterpret_cast<const void*>(birnn_main),
                      hipFuncAttributeMaxDynamicSharedMemorySize,
                      (int)(LDSW_TOTAL * sizeof(float)));
  void* args[] = { (void*)&p };
  hipLaunchCooperativeKernel(reinterpret_cast<void*>(birnn_main),
                             dim3(256), dim3(512), args,
                             (unsigned)(LDSW_TOTAL * sizeof(float)), stream);

  combine_kernel<<<dim3(Bx * Sx * Fx / 256), dim3(256), 0, stream>>>(
      (float*)d_out, ws + PARTB_OFF, (const float*)d_in[15]);
}